// Round 3
// baseline (494.798 us; speedup 1.0000x reference)
//
#include <hip/hip_runtime.h>
#include <hip/hip_bf16.h>
#include <math.h>

#define NN 100000
#define EE 1600000
#define DD 128
#define HH 8
#define LDW 136   // padded LDS row stride (bf16 elems) for 128-wide W tiles
#define BSH 9     // bucket shift: 512 nodes per bucket
#define NB 196    // ceil(NN / 512)
#define EPB 8192  // edges per block in bucket pass A

typedef short short8 __attribute__((ext_vector_type(8)));
typedef float f32x4 __attribute__((ext_vector_type(4)));

__device__ __forceinline__ unsigned short f2bf(float f) {  // RNE float->bf16 bits
    unsigned int u = __float_as_uint(f);
    u += 0x7fffu + ((u >> 16) & 1u);
    return (unsigned short)(u >> 16);
}
__device__ __forceinline__ float bf2f(unsigned short h) {
    return __uint_as_float((unsigned int)h << 16);
}
// 8 floats -> bf16 hi + residual-lo vectors
__device__ __forceinline__ void cvt8(const float4& a, const float4& b,
                                     short8& h8, short8& l8) {
    float vals[8] = {a.x, a.y, a.z, a.w, b.x, b.y, b.z, b.w};
    #pragma unroll
    for (int j = 0; j < 8; j++) {
        unsigned short hi = f2bf(vals[j]);
        h8[j] = (short)hi;
        l8[j] = (short)f2bf(vals[j] - bf2f(hi));
    }
}

// ---------------------------------------------------------------------------
// Fold rel_att/rel_msg into Wk/Wv; emit all 4 weights in [j][c] order as
// bf16 hi/lo pairs, plus effective biases. which: 0=q, 1=k, 2=v, 3=a
// ---------------------------------------------------------------------------
__global__ void prep_weights(const float* __restrict__ Wq, const float* __restrict__ Wk,
                             const float* __restrict__ Wv, const float* __restrict__ Wa,
                             const float* __restrict__ bq, const float* __restrict__ bk,
                             const float* __restrict__ bv, const float* __restrict__ ba,
                             const float* __restrict__ rel_att, const float* __restrict__ rel_msg,
                             unsigned short* __restrict__ WH, unsigned short* __restrict__ WL,
                             float* __restrict__ BE) {
    int o = blockIdx.x * 256 + threadIdx.x;   // [j][c], j=out col, c=in dim
    int j = o >> 7, c = o & 127;
    int which = blockIdx.y;
    float val;
    if (which == 0) {
        val = Wq[o];
        if (o < 128) BE[o] = bq[o];
    } else if (which == 3) {
        val = Wa[o];
        if (o < 128) BE[384 + o] = ba[o];
    } else {
        const float* rel = (which == 1) ? rel_att : rel_msg;
        const float* W   = (which == 1) ? Wk : Wv;
        const float* b   = (which == 1) ? bk : bv;
        int hh = j >> 4, e = j & 15;
        val = 0.f;
        #pragma unroll
        for (int d = 0; d < 16; d++)
            val += rel[hh * 256 + d * 16 + e] * W[(hh * 16 + d) * 128 + c];
        if (c == 0) {
            float bacc = 0.f;
            #pragma unroll
            for (int d = 0; d < 16; d++)
                bacc += b[hh * 16 + d] * rel[hh * 256 + d * 16 + e];
            BE[which * 128 + j] = bacc;
        }
    }
    unsigned short hi = f2bf(val);
    unsigned short lo = f2bf(val - bf2f(hi));
    WH[which * 16384 + o] = hi;
    WL[which * 16384 + o] = lo;
}

// ---------------------------------------------------------------------------
// Register-A MFMA GEMM, bf16 hi/lo split (R6-proven). In-place safe.
// kv output layout (wi=1,2): interleaved per 4-elem group so fused_attn can
// read each lane's k4+v4 with ONE dwordx4:
//   kv[row][ (col>>2)*8 + (wi-1)*4 + (col&3) ]
// ---------------------------------------------------------------------------
__launch_bounds__(256, 2)
__global__ void gemm_reg(const float* __restrict__ x,
                         const unsigned short* __restrict__ WH,
                         const unsigned short* __restrict__ WL,
                         const float* __restrict__ BE, int nw,
                         float* __restrict__ out0, unsigned short* __restrict__ kvout,
                         const float* __restrict__ resid, const float* __restrict__ skip) {
    __shared__ unsigned short wh[128 * LDW];
    __shared__ unsigned short wl[128 * LDW];
    int tid = threadIdx.x;
    int wv = tid >> 6, lane = tid & 63;
    int lrow = lane & 15, quad = lane >> 4;
    int base = blockIdx.x * 128;

    // ---- load this wave's 32 x-rows into A-fragment registers (hi/lo) ----
    short8 ah[2][4], al[2][4];
    float4 fz = {0.f, 0.f, 0.f, 0.f};
    #pragma unroll
    for (int mt = 0; mt < 2; mt++) {
        int row = base + wv * 32 + mt * 16 + lrow;
        const float* xr = x + (size_t)row * 128;
        bool ok = (row < NN);
        #pragma unroll
        for (int kc = 0; kc < 4; kc++) {
            int off = kc * 32 + quad * 8;
            float4 a = ok ? *(const float4*)&xr[off] : fz;
            float4 b = ok ? *(const float4*)&xr[off + 4] : fz;
            cvt8(a, b, ah[mt][kc], al[mt][kc]);
        }
    }

    float alpha = 1.f, beta = 0.f;
    if (resid) {
        float sv = skip[0];
        alpha = 1.f / (1.f + expf(-sv));
        beta = 1.f - alpha;
    }

    for (int wi = 0; wi < nw; wi++) {
        __syncthreads();   // prior-phase W readers done
        const unsigned short* WHp = WH + wi * 16384;
        const unsigned short* WLp = WL + wi * 16384;
        for (int i = tid; i < 128 * 16; i += 256) {
            int n = i >> 4, kq = (i & 15) << 3;
            *(uint4*)&wh[n * LDW + kq] = *(const uint4*)&WHp[n * 128 + kq];
            *(uint4*)&wl[n * LDW + kq] = *(const uint4*)&WLp[n * 128 + kq];
        }
        __syncthreads();

        f32x4 zero4 = {0.f, 0.f, 0.f, 0.f};
        f32x4 acc[2][8];
        #pragma unroll
        for (int a = 0; a < 2; a++)
            #pragma unroll
            for (int b = 0; b < 8; b++) acc[a][b] = zero4;

        #pragma unroll
        for (int kc = 0; kc < 4; kc++) {
            #pragma unroll
            for (int nt = 0; nt < 8; nt++) {
                int koff = kc * 32 + quad * 8;
                int brow = (nt * 16 + lrow) * LDW + koff;
                short8 bh = *(const short8*)&wh[brow];
                short8 bl = *(const short8*)&wl[brow];
                acc[0][nt] = __builtin_amdgcn_mfma_f32_16x16x32_bf16(ah[0][kc], bh, acc[0][nt], 0, 0, 0);
                acc[1][nt] = __builtin_amdgcn_mfma_f32_16x16x32_bf16(ah[1][kc], bh, acc[1][nt], 0, 0, 0);
                acc[0][nt] = __builtin_amdgcn_mfma_f32_16x16x32_bf16(al[0][kc], bh, acc[0][nt], 0, 0, 0);
                acc[1][nt] = __builtin_amdgcn_mfma_f32_16x16x32_bf16(al[1][kc], bh, acc[1][nt], 0, 0, 0);
                acc[0][nt] = __builtin_amdgcn_mfma_f32_16x16x32_bf16(ah[0][kc], bl, acc[0][nt], 0, 0, 0);
                acc[1][nt] = __builtin_amdgcn_mfma_f32_16x16x32_bf16(ah[1][kc], bl, acc[1][nt], 0, 0, 0);
            }
        }

        const float* be = BE + wi * 128;
        #pragma unroll
        for (int nt = 0; nt < 8; nt++) {
            int col = nt * 16 + lrow;
            float bb = be[col];
            #pragma unroll
            for (int mt = 0; mt < 2; mt++) {
                int r0 = base + wv * 32 + mt * 16 + quad * 4;
                #pragma unroll
                for (int rg = 0; rg < 4; rg++) {
                    int row = r0 + rg;
                    if (row < NN) {
                        float val = acc[mt][nt][rg] + bb;
                        if (wi == 0) {
                            if (resid) val = alpha * val + beta * resid[(size_t)row * 128 + col];
                            out0[(size_t)row * 128 + col] = val;
                        } else {
                            int pos = ((col >> 2) << 3) + ((wi - 1) << 2) + (col & 3);
                            kvout[(size_t)row * 256 + pos] = f2bf(val);
                        }
                    }
                }
            }
        }
    }
}

// ======================= CSR build: 2-pass bucket sort =====================
// Pass A: partition edges into NB buckets of 512 dst-nodes, LDS-staged so
// global writes are coalesced runs. Pass B: per-bucket counting sort in LDS,
// emits offs (inclusive ends) + sorted_src with writes confined to the
// bucket's own 32KB window (no cross-block line sharing).
// packed edge = (dst_local:9 << 17) | src:17   (both fit: N < 2^17)
// ---------------------------------------------------------------------------
__global__ void bucket_hist(const int* __restrict__ dst, int* __restrict__ bcnt) {
    __shared__ int lh[NB];
    int t = threadIdx.x;
    for (int i = t; i < NB; i += 256) lh[i] = 0;
    __syncthreads();
    int base = blockIdx.x * EPB;
    int cnt = min(EPB, EE - base);
    for (int i = t; i < cnt; i += 256)
        atomicAdd(&lh[dst[base + i] >> BSH], 1);
    __syncthreads();
    for (int i = t; i < NB; i += 256)
        if (lh[i]) atomicAdd(&bcnt[i], lh[i]);
}

// exclusive scan of bcnt[NB] -> btail (running cursors) + sbase (fixed bases)
__global__ void bucket_scan(const int* __restrict__ bcnt, int* __restrict__ btail,
                            int* __restrict__ sbase) {
    __shared__ int buf[2][256];
    int t = threadIdx.x;
    int v = (t < NB) ? bcnt[t] : 0;
    buf[0][t] = v;
    __syncthreads();
    int sb = 0;
    #pragma unroll
    for (int d = 1; d < 256; d <<= 1) {
        int x = buf[sb][t];
        if (t >= d) x += buf[sb][t - d];
        buf[sb ^ 1][t] = x;
        __syncthreads();
        sb ^= 1;
    }
    if (t < NB) {
        int excl = buf[sb][t] - v;
        btail[t] = excl;
        sbase[t] = excl;
    }
    if (t == 0) sbase[NB] = EE;
}

__launch_bounds__(256, 1)
__global__ void bucket_scatter(const int* __restrict__ src, const int* __restrict__ dst,
                               int* __restrict__ btail, int* __restrict__ packed) {
    __shared__ int2 staged[EPB];                       // 64 KB
    __shared__ int hist[NB], lstart[NB], cursor[NB], gbase[NB];
    __shared__ int sbuf[2][256];
    int t = threadIdx.x;
    for (int i = t; i < NB; i += 256) hist[i] = 0;
    __syncthreads();
    int base = blockIdx.x * EPB;
    int cnt = min(EPB, EE - base);
    for (int i = t; i < cnt; i += 256)
        atomicAdd(&hist[dst[base + i] >> BSH], 1);
    __syncthreads();
    // exclusive scan of hist -> lstart, init cursor
    int v = (t < NB) ? hist[t] : 0;
    sbuf[0][t] = v;
    __syncthreads();
    int sb = 0;
    #pragma unroll
    for (int d = 1; d < 256; d <<= 1) {
        int x = sbuf[sb][t];
        if (t >= d) x += sbuf[sb][t - d];
        sbuf[sb ^ 1][t] = x;
        __syncthreads();
        sb ^= 1;
    }
    if (t < NB) {
        lstart[t] = sbuf[sb][t] - v;
        cursor[t] = sbuf[sb][t] - v;
    }
    __syncthreads();
    // rank + stage (re-read edges; L2-hot)
    for (int i = t; i < cnt; i += 256) {
        int d = dst[base + i], s = src[base + i];
        int r = atomicAdd(&cursor[d >> BSH], 1);
        staged[r] = make_int2(s, d);
    }
    // reserve global runs
    __syncthreads();
    for (int i = t; i < NB; i += 256) {
        int c = hist[i];
        if (c) gbase[i] = atomicAdd(&btail[i], c);
    }
    __syncthreads();
    // coalesced run writes
    for (int i = t; i < cnt; i += 256) {
        int2 e = staged[i];
        int b = e.y >> BSH;
        packed[gbase[b] + (i - lstart[b])] = ((e.y & 511) << 17) | e.x;
    }
}

__launch_bounds__(512, 2)
__global__ void node_sort(const int* __restrict__ packed, const int* __restrict__ sbase,
                          int* __restrict__ offs, int* __restrict__ sorted_src) {
    __shared__ int hist[512], cursor[512];
    __shared__ int scn[2][512];
    int t = threadIdx.x;
    int b = blockIdx.x;
    int s0 = sbase[b], s1 = sbase[b + 1];
    hist[t] = 0;
    __syncthreads();
    for (int e = s0 + t; e < s1; e += 512)
        atomicAdd(&hist[packed[e] >> 17], 1);
    __syncthreads();
    int v = hist[t];
    scn[0][t] = v;
    __syncthreads();
    int sb = 0;
    #pragma unroll
    for (int d = 1; d < 512; d <<= 1) {
        int x = scn[sb][t];
        if (t >= d) x += scn[sb][t - d];
        scn[sb ^ 1][t] = x;
        __syncthreads();
        sb ^= 1;
    }
    int incl = scn[sb][t];
    int node = (b << BSH) + t;
    if (node < NN) offs[node] = s0 + incl;    // inclusive end, CSR semantics
    cursor[t] = s0 + incl - v;                // exclusive start
    __syncthreads();
    for (int e = s0 + t; e < s1; e += 512) {
        int p = packed[e];
        int pos = atomicAdd(&cursor[p >> 17], 1);
        sorted_src[pos] = p & 0x1FFFF;        // writes confined to 32KB window
    }
}

// ---------------------------------------------------------------------------
// Fused per-dst attention, single pass, bf16 packed interleaved kv[n][256]:
// group g (=sl) holds {k[4g..4g+3], v[4g..4g+3]} at byte offset g*16 -> one
// dwordx4 per lane per edge (512B contiguous per half-wave request).
// One wave per node. 4 elems/lane: sl=lane&31 owns elems {4sl..4sl+3},
// head = sl>>2; the two half-waves process edges 2i and 2i+1.
// exp via native v_exp_f32: log2(e) folded into the q prescale.
// Divergence-free: all 64 lanes active every iteration; odd-cnt tail is a
// duplicated edge with weight 0. q fp32 (may alias t: read before write).
// launch_bounds(256,8): VGPR=16/LDS=0 -> nothing limits 8 wg/CU; gather-
// latency-bound loop wants max wave-level parallelism (32 waves/CU).
// ---------------------------------------------------------------------------
__launch_bounds__(256, 8)
__global__ void fused_attn(const float* __restrict__ q,
                           const unsigned short* __restrict__ kv,
                           const int* __restrict__ offs, const int* __restrict__ sorted_src,
                           const float* __restrict__ rel_pri, float* __restrict__ t) {
    int wave = threadIdx.x >> 6, lane = threadIdx.x & 63;
    int n = blockIdx.x * 4 + wave;
    if (n >= NN) return;
    int half = lane >> 5;
    int sl = lane & 31;
    int hh = sl >> 2;
    int start = (n > 0) ? offs[n - 1] : 0;
    int cnt = offs[n] - start;

    float4 q4 = *(const float4*)&q[(size_t)n * 128 + sl * 4];
    // fold rel_pri/sqrt(dk) AND log2(e) into the q prescale: exp(p)=exp2(p')
    float scale = rel_pri[hh] * 0.25f * 1.44269504088896340736f;
    q4.x *= scale; q4.y *= scale; q4.z *= scale; q4.w *= scale;

    const unsigned short* kvp = kv + sl * 8;   // lane-fixed sub-offset

    float4 o4 = {0.f, 0.f, 0.f, 0.f};
    float denom = 0.f;

    int nIter = (cnt + 1) >> 1;
    #pragma unroll 4
    for (int it = 0; it < nIter; it++) {
        int j = 2 * it + half;
        float wgt = (j < cnt) ? 1.f : 0.f;
        int jj = (j < cnt) ? j : (cnt - 1);
        int s = sorted_src[start + jj];
        uint4 kvb = *(const uint4*)(kvp + (size_t)s * 256);  // k4 | v4, 16B
        float p = q4.x * bf2f((unsigned short)(kvb.x & 0xffff))
                + q4.y * bf2f((unsigned short)(kvb.x >> 16))
                + q4.z * bf2f((unsigned short)(kvb.y & 0xffff))
                + q4.w * bf2f((unsigned short)(kvb.y >> 16));
        p += __shfl_xor(p, 1);
        p += __shfl_xor(p, 2);
        float e = __builtin_amdgcn_exp2f(p) * wgt;   // native v_exp_f32
        denom += e;
        o4.x = fmaf(bf2f((unsigned short)(kvb.z & 0xffff)), e, o4.x);
        o4.y = fmaf(bf2f((unsigned short)(kvb.z >> 16)),    e, o4.y);
        o4.z = fmaf(bf2f((unsigned short)(kvb.w & 0xffff)), e, o4.z);
        o4.w = fmaf(bf2f((unsigned short)(kvb.w >> 16)),    e, o4.w);
    }

    // combine the two halves (all 64 lanes active)
    denom += __shfl_xor(denom, 32);
    o4.x += __shfl_xor(o4.x, 32);
    o4.y += __shfl_xor(o4.y, 32);
    o4.z += __shfl_xor(o4.z, 32);
    o4.w += __shfl_xor(o4.w, 32);

    if (half == 0) {
        float inv = (cnt > 0) ? 1.f / denom : 0.f;
        o4.x *= inv; o4.y *= inv; o4.z *= inv; o4.w *= inv;
        *(float4*)&t[(size_t)n * 128 + sl * 4] = o4;
    }
}

// ---------------------------------------------------------------------------
extern "C" void kernel_launch(void* const* d_in, const int* in_sizes, int n_in,
                              void* d_out, int out_size, void* d_ws, size_t ws_size,
                              hipStream_t stream) {
    const float* h    = (const float*)d_in[0];
    const int*   src  = (const int*)d_in[1];
    const int*   dst  = (const int*)d_in[2];
    const float* Wk   = (const float*)d_in[3];
    const float* bk   = (const float*)d_in[4];
    const float* Wq   = (const float*)d_in[5];
    const float* bq   = (const float*)d_in[6];
    const float* Wv   = (const float*)d_in[7];
    const float* bv   = (const float*)d_in[8];
    const float* Wa   = (const float*)d_in[9];
    const float* ba   = (const float*)d_in[10];
    const float* rel_att = (const float*)d_in[11];
    const float* rel_msg = (const float*)d_in[12];
    const float* rel_pri = (const float*)d_in[13];
    const float* skip    = (const float*)d_in[14];
    float* out = (float*)d_out;

    unsigned short* kvbuf = (unsigned short*)d_ws;            // N*256 bf16
    float* BE   = (float*)(kvbuf + (size_t)NN * 256);         // 4*128
    int* scratch = (int*)(BE + 512);                          // old deg slot (N ints)
    int* bcnt  = scratch;                                     // NB
    int* btail = bcnt + NB;                                   // NB
    int* sbase = btail + NB;                                  // NB+1
    int* offs  = scratch + NN;                                // N
    int* bsum  = offs + NN;                                   // 128 (unused, keeps layout)
    int* sorted_src = bsum + 128;                             // E
    unsigned short* WH = (unsigned short*)(sorted_src + EE);  // 4*16384 bf16
    unsigned short* WL = WH + 4 * 16384;                      // 4*16384 bf16
    // packed edges alias kvbuf: dead until gemm1, 6.4MB <= 51.2MB
    int* packed = (int*)kvbuf;
    float* q = out;                                // q lives in d_out; t aliases q
    float* t = out;

    const int A_BLOCKS = (EE + EPB - 1) / EPB;     // 196
    const int GEMM_BLOCKS = (NN + 127) / 128;      // 782

    prep_weights<<<dim3(64, 4), 256, 0, stream>>>(Wq, Wk, Wv, Wa, bq, bk, bv, ba,
                                                  rel_att, rel_msg, WH, WL, BE);
    // CSR build: 2-pass bucket sort
    hipMemsetAsync(bcnt, 0, NB * sizeof(int), stream);
    bucket_hist<<<A_BLOCKS, 256, 0, stream>>>(dst, bcnt);
    bucket_scan<<<1, 256, 0, stream>>>(bcnt, btail, sbase);
    bucket_scatter<<<A_BLOCKS, 256, 0, stream>>>(src, dst, btail, packed);
    node_sort<<<NB, 512, 0, stream>>>(packed, sbase, offs, sorted_src);

    // fused q|k|v projection: q fp32 -> d_out, k/v bf16 -> packed interleaved kv
    gemm_reg<<<GEMM_BLOCKS, 256, 0, stream>>>(h, WH, WL, BE, 3, q, kvbuf,
                                              nullptr, nullptr);
    // fused single-pass attention (no atomics)
    fused_attn<<<(NN + 3) / 4, 256, 0, stream>>>(q, kvbuf, offs, sorted_src,
                                                 rel_pri, t);
    // final projection + skip-gate mix (in-place on d_out)
    gemm_reg<<<GEMM_BLOCKS, 256, 0, stream>>>(t, WH + 3 * 16384, WL + 3 * 16384,
                                              BE + 384, 1, out, nullptr,
                                              h, skip);
}

// Round 4
// 493.252 us; speedup vs baseline: 1.0031x; 1.0031x over previous
//
#include <hip/hip_runtime.h>
#include <hip/hip_bf16.h>
#include <math.h>

#define NN 100000
#define EE 1600000
#define DD 128
#define HH 8
#define LDW 136   // padded LDS row stride (bf16 elems) for 128-wide W tiles
#define BSH 9     // bucket shift: 512 nodes per bucket
#define NB 196    // ceil(NN / 512)
#define EPB 8192  // edges per block in bucket pass A
#define A_BLOCKS 196   // (EE + EPB - 1) / EPB
#define GEMM_BLOCKS 782  // (NN + 127) / 128

typedef short short8 __attribute__((ext_vector_type(8)));
typedef float f32x4 __attribute__((ext_vector_type(4)));

__device__ __forceinline__ unsigned short f2bf(float f) {  // RNE float->bf16 bits
    unsigned int u = __float_as_uint(f);
    u += 0x7fffu + ((u >> 16) & 1u);
    return (unsigned short)(u >> 16);
}
__device__ __forceinline__ float bf2f(unsigned short h) {
    return __uint_as_float((unsigned int)h << 16);
}
// 8 floats -> bf16 hi + residual-lo vectors
__device__ __forceinline__ void cvt8(const float4& a, const float4& b,
                                     short8& h8, short8& l8) {
    float vals[8] = {a.x, a.y, a.z, a.w, b.x, b.y, b.z, b.w};
    #pragma unroll
    for (int j = 0; j < 8; j++) {
        unsigned short hi = f2bf(vals[j]);
        h8[j] = (short)hi;
        l8[j] = (short)f2bf(vals[j] - bf2f(hi));
    }
}

// ---------------------------------------------------------------------------
// prep_weights body: fold rel_att/rel_msg into Wk/Wv; emit all 4 weights in
// [j][c] order as bf16 hi/lo pairs + effective biases. which: 0=q,1=k,2=v,3=a
// ---------------------------------------------------------------------------
__device__ __forceinline__ void prep_work(int which, int bx,
                             const float* __restrict__ Wq, const float* __restrict__ Wk,
                             const float* __restrict__ Wv, const float* __restrict__ Wa,
                             const float* __restrict__ bq, const float* __restrict__ bk,
                             const float* __restrict__ bv, const float* __restrict__ ba,
                             const float* __restrict__ rel_att, const float* __restrict__ rel_msg,
                             unsigned short* __restrict__ WH, unsigned short* __restrict__ WL,
                             float* __restrict__ BE) {
    int o = bx * 256 + threadIdx.x;   // [j][c], j=out col, c=in dim
    int j = o >> 7, c = o & 127;
    float val;
    if (which == 0) {
        val = Wq[o];
        if (o < 128) BE[o] = bq[o];
    } else if (which == 3) {
        val = Wa[o];
        if (o < 128) BE[384 + o] = ba[o];
    } else {
        const float* rel = (which == 1) ? rel_att : rel_msg;
        const float* W   = (which == 1) ? Wk : Wv;
        const float* b   = (which == 1) ? bk : bv;
        int hh = j >> 4, e = j & 15;
        val = 0.f;
        #pragma unroll
        for (int d = 0; d < 16; d++)
            val += rel[hh * 256 + d * 16 + e] * W[(hh * 16 + d) * 128 + c];
        if (c == 0) {
            float bacc = 0.f;
            #pragma unroll
            for (int d = 0; d < 16; d++)
                bacc += b[hh * 16 + d] * rel[hh * 256 + d * 16 + e];
            BE[which * 128 + j] = bacc;
        }
    }
    unsigned short hi = f2bf(val);
    unsigned short lo = f2bf(val - bf2f(hi));
    WH[which * 16384 + o] = hi;
    WL[which * 16384 + o] = lo;
}

// fused: blocks [0,256) do prep_weights (which = bid>>6), blocks [256,256+196)
// do the bucket histogram. Independent work, overlapped in one dispatch.
__global__ void prep_hist(const float* __restrict__ Wq, const float* __restrict__ Wk,
                          const float* __restrict__ Wv, const float* __restrict__ Wa,
                          const float* __restrict__ bq, const float* __restrict__ bk,
                          const float* __restrict__ bv, const float* __restrict__ ba,
                          const float* __restrict__ rel_att, const float* __restrict__ rel_msg,
                          unsigned short* __restrict__ WH, unsigned short* __restrict__ WL,
                          float* __restrict__ BE,
                          const int* __restrict__ dst, int* __restrict__ bcnt) {
    __shared__ int lh[NB];
    int bid = blockIdx.x;
    if (bid < 256) {
        prep_work(bid >> 6, bid & 63, Wq, Wk, Wv, Wa, bq, bk, bv, ba,
                  rel_att, rel_msg, WH, WL, BE);
    } else {
        int t = threadIdx.x;
        for (int i = t; i < NB; i += 256) lh[i] = 0;
        __syncthreads();
        int base = (bid - 256) * EPB;
        int cnt = min(EPB, EE - base);
        for (int i = t; i < cnt; i += 256)
            atomicAdd(&lh[dst[base + i] >> BSH], 1);
        __syncthreads();
        for (int i = t; i < NB; i += 256)
            if (lh[i]) atomicAdd(&bcnt[i], lh[i]);
    }
}

// ---------------------------------------------------------------------------
// Register-A MFMA GEMM body, bf16 hi/lo split (R6-proven). In-place safe.
// kv output layout (wi=1,2): interleaved per 4-elem group so fused_attn can
// read each lane's k4+v4 with ONE dwordx4:
//   kv[row][ (col>>2)*8 + (wi-1)*4 + (col&3) ]
// smemc: >= 69632 bytes, 16B-aligned.
// ---------------------------------------------------------------------------
__device__ __forceinline__ void gemm_body(char* smemc, int base,
                         const float* __restrict__ x,
                         const unsigned short* __restrict__ WH,
                         const unsigned short* __restrict__ WL,
                         const float* __restrict__ BE, int nw,
                         float* __restrict__ out0, unsigned short* __restrict__ kvout,
                         const float* __restrict__ resid, const float* __restrict__ skip) {
    unsigned short* wh = (unsigned short*)smemc;           // 128*LDW
    unsigned short* wl = wh + 128 * LDW;                   // 128*LDW
    int tid = threadIdx.x;
    int wv = tid >> 6, lane = tid & 63;
    int lrow = lane & 15, quad = lane >> 4;

    // ---- load this wave's 32 x-rows into A-fragment registers (hi/lo) ----
    short8 ah[2][4], al[2][4];
    float4 fz = {0.f, 0.f, 0.f, 0.f};
    #pragma unroll
    for (int mt = 0; mt < 2; mt++) {
        int row = base + wv * 32 + mt * 16 + lrow;
        const float* xr = x + (size_t)row * 128;
        bool ok = (row < NN);
        #pragma unroll
        for (int kc = 0; kc < 4; kc++) {
            int off = kc * 32 + quad * 8;
            float4 a = ok ? *(const float4*)&xr[off] : fz;
            float4 b = ok ? *(const float4*)&xr[off + 4] : fz;
            cvt8(a, b, ah[mt][kc], al[mt][kc]);
        }
    }

    float alpha = 1.f, beta = 0.f;
    if (resid) {
        float sv = skip[0];
        alpha = 1.f / (1.f + expf(-sv));
        beta = 1.f - alpha;
    }

    for (int wi = 0; wi < nw; wi++) {
        __syncthreads();   // prior-phase W readers done
        const unsigned short* WHp = WH + wi * 16384;
        const unsigned short* WLp = WL + wi * 16384;
        for (int i = tid; i < 128 * 16; i += 256) {
            int n = i >> 4, kq = (i & 15) << 3;
            *(uint4*)&wh[n * LDW + kq] = *(const uint4*)&WHp[n * 128 + kq];
            *(uint4*)&wl[n * LDW + kq] = *(const uint4*)&WLp[n * 128 + kq];
        }
        __syncthreads();

        f32x4 zero4 = {0.f, 0.f, 0.f, 0.f};
        f32x4 acc[2][8];
        #pragma unroll
        for (int a = 0; a < 2; a++)
            #pragma unroll
            for (int b = 0; b < 8; b++) acc[a][b] = zero4;

        #pragma unroll
        for (int kc = 0; kc < 4; kc++) {
            #pragma unroll
            for (int nt = 0; nt < 8; nt++) {
                int koff = kc * 32 + quad * 8;
                int brow = (nt * 16 + lrow) * LDW + koff;
                short8 bh = *(const short8*)&wh[brow];
                short8 bl = *(const short8*)&wl[brow];
                acc[0][nt] = __builtin_amdgcn_mfma_f32_16x16x32_bf16(ah[0][kc], bh, acc[0][nt], 0, 0, 0);
                acc[1][nt] = __builtin_amdgcn_mfma_f32_16x16x32_bf16(ah[1][kc], bh, acc[1][nt], 0, 0, 0);
                acc[0][nt] = __builtin_amdgcn_mfma_f32_16x16x32_bf16(al[0][kc], bh, acc[0][nt], 0, 0, 0);
                acc[1][nt] = __builtin_amdgcn_mfma_f32_16x16x32_bf16(al[1][kc], bh, acc[1][nt], 0, 0, 0);
                acc[0][nt] = __builtin_amdgcn_mfma_f32_16x16x32_bf16(ah[0][kc], bl, acc[0][nt], 0, 0, 0);
                acc[1][nt] = __builtin_amdgcn_mfma_f32_16x16x32_bf16(ah[1][kc], bl, acc[1][nt], 0, 0, 0);
            }
        }

        const float* be = BE + wi * 128;
        #pragma unroll
        for (int nt = 0; nt < 8; nt++) {
            int col = nt * 16 + lrow;
            float bb = be[col];
            #pragma unroll
            for (int mt = 0; mt < 2; mt++) {
                int r0 = base + wv * 32 + mt * 16 + quad * 4;
                #pragma unroll
                for (int rg = 0; rg < 4; rg++) {
                    int row = r0 + rg;
                    if (row < NN) {
                        float val = acc[mt][nt][rg] + bb;
                        if (wi == 0) {
                            if (resid) val = alpha * val + beta * resid[(size_t)row * 128 + col];
                            out0[(size_t)row * 128 + col] = val;
                        } else {
                            int pos = ((col >> 2) << 3) + ((wi - 1) << 2) + (col & 3);
                            kvout[(size_t)row * 256 + pos] = f2bf(val);
                        }
                    }
                }
            }
        }
    }
}

__launch_bounds__(256, 2)
__global__ void gemm_reg(const float* __restrict__ x,
                         const unsigned short* __restrict__ WH,
                         const unsigned short* __restrict__ WL,
                         const float* __restrict__ BE, int nw,
                         float* __restrict__ out0, unsigned short* __restrict__ kvout,
                         const float* __restrict__ resid, const float* __restrict__ skip) {
    __shared__ __align__(16) char smem[69632];
    gemm_body(smem, blockIdx.x * 128, x, WH, WL, BE, nw, out0, kvout, resid, skip);
}

// ======================= CSR build: 2-pass bucket sort =====================
// exclusive scan of bcnt[NB] -> btail (running cursors) + sbase (fixed bases)
__global__ void bucket_scan(const int* __restrict__ bcnt, int* __restrict__ btail,
                            int* __restrict__ sbase) {
    __shared__ int buf[2][256];
    int t = threadIdx.x;
    int v = (t < NB) ? bcnt[t] : 0;
    buf[0][t] = v;
    __syncthreads();
    int sb = 0;
    #pragma unroll
    for (int d = 1; d < 256; d <<= 1) {
        int x = buf[sb][t];
        if (t >= d) x += buf[sb][t - d];
        buf[sb ^ 1][t] = x;
        __syncthreads();
        sb ^= 1;
    }
    if (t < NB) {
        int excl = buf[sb][t] - v;
        btail[t] = excl;
        sbase[t] = excl;
    }
    if (t == 0) sbase[NB] = EE;
}

// scatter body. smemc layout (70720B total, 16B-aligned):
//   staged int2[8192] @0 (64KB) | hist[NB] | lstart[NB] | cursor[NB] |
//   gbase[NB] | sbuf[2][256]
__device__ __forceinline__ void scatter_work(char* smemc, int bid,
                               const int* __restrict__ src, const int* __restrict__ dst,
                               int* __restrict__ btail, int* __restrict__ packed) {
    int2* staged = (int2*)smemc;
    int* hist   = (int*)(smemc + 65536);
    int* lstart = hist + NB;
    int* cursor = lstart + NB;
    int* gbase  = cursor + NB;
    int* sbuf   = gbase + NB;   // [2][256]
    int t = threadIdx.x;
    for (int i = t; i < NB; i += 256) hist[i] = 0;
    __syncthreads();
    int base = bid * EPB;
    int cnt = min(EPB, EE - base);
    for (int i = t; i < cnt; i += 256)
        atomicAdd(&hist[dst[base + i] >> BSH], 1);
    __syncthreads();
    // exclusive scan of hist -> lstart, init cursor
    int v = (t < NB) ? hist[t] : 0;
    sbuf[t] = v;
    __syncthreads();
    int sb = 0;
    #pragma unroll
    for (int d = 1; d < 256; d <<= 1) {
        int x = sbuf[sb * 256 + t];
        if (t >= d) x += sbuf[sb * 256 + t - d];
        sbuf[(sb ^ 1) * 256 + t] = x;
        __syncthreads();
        sb ^= 1;
    }
    if (t < NB) {
        lstart[t] = sbuf[sb * 256 + t] - v;
        cursor[t] = sbuf[sb * 256 + t] - v;
    }
    __syncthreads();
    // rank + stage (re-read edges; L2-hot)
    for (int i = t; i < cnt; i += 256) {
        int d = dst[base + i], s = src[base + i];
        int r = atomicAdd(&cursor[d >> BSH], 1);
        staged[r] = make_int2(s, d);
    }
    // reserve global runs
    __syncthreads();
    for (int i = t; i < NB; i += 256) {
        int c = hist[i];
        if (c) gbase[i] = atomicAdd(&btail[i], c);
    }
    __syncthreads();
    // coalesced run writes
    for (int i = t; i < cnt; i += 256) {
        int2 e = staged[i];
        int b = e.y >> BSH;
        packed[gbase[b] + (i - lstart[b])] = ((e.y & 511) << 17) | e.x;
    }
}

__launch_bounds__(256, 1)
__global__ void bucket_scatter(const int* __restrict__ src, const int* __restrict__ dst,
                               int* __restrict__ btail, int* __restrict__ packed) {
    __shared__ __align__(16) char smem[70720];
    scatter_work(smem, blockIdx.x, src, dst, btail, packed);
}

// fused: blocks [0,196) run bucket_scatter (critical path to node_sort),
// blocks [196, 196+782) run the 3-way qkv GEMM. Independent (packed is
// disjoint from kvbuf in this path). Union LDS 70720B -> 2 blocks/CU.
__launch_bounds__(256, 2)
__global__ void gemm0_scatter(const float* __restrict__ x,
                              const unsigned short* __restrict__ WH,
                              const unsigned short* __restrict__ WL,
                              const float* __restrict__ BE,
                              float* __restrict__ q, unsigned short* __restrict__ kvout,
                              const int* __restrict__ src, const int* __restrict__ dst,
                              int* __restrict__ btail, int* __restrict__ packed) {
    __shared__ __align__(16) char smem[70720];
    if (blockIdx.x < A_BLOCKS)
        scatter_work(smem, blockIdx.x, src, dst, btail, packed);
    else
        gemm_body(smem, (blockIdx.x - A_BLOCKS) * 128, x, WH, WL, BE, 3,
                  q, kvout, nullptr, nullptr);
}

__launch_bounds__(512, 2)
__global__ void node_sort(const int* __restrict__ packed, const int* __restrict__ sbase,
                          int* __restrict__ offs, int* __restrict__ sorted_src) {
    __shared__ int hist[512], cursor[512];
    __shared__ int scn[2][512];
    int t = threadIdx.x;
    int b = blockIdx.x;
    int s0 = sbase[b], s1 = sbase[b + 1];
    hist[t] = 0;
    __syncthreads();
    for (int e = s0 + t; e < s1; e += 512)
        atomicAdd(&hist[packed[e] >> 17], 1);
    __syncthreads();
    int v = hist[t];
    scn[0][t] = v;
    __syncthreads();
    int sb = 0;
    #pragma unroll
    for (int d = 1; d < 512; d <<= 1) {
        int x = scn[sb][t];
        if (t >= d) x += scn[sb][t - d];
        scn[sb ^ 1][t] = x;
        __syncthreads();
        sb ^= 1;
    }
    int incl = scn[sb][t];
    int node = (b << BSH) + t;
    if (node < NN) offs[node] = s0 + incl;    // inclusive end, CSR semantics
    cursor[t] = s0 + incl - v;                // exclusive start
    __syncthreads();
    for (int e = s0 + t; e < s1; e += 512) {
        int p = packed[e];
        int pos = atomicAdd(&cursor[p >> 17], 1);
        sorted_src[pos] = p & 0x1FFFF;        // writes confined to 32KB window
    }
}

// ---------------------------------------------------------------------------
// Fused per-dst attention, single pass, bf16 packed interleaved kv[n][256]:
// group g (=sl) holds {k[4g..4g+3], v[4g..4g+3]} at byte offset g*16 -> one
// dwordx4 per lane per edge (512B contiguous per half-wave request).
// 4 consecutive nodes per wave (16 per block): amortizes block churn and
// smooths per-wave degree variance. 4 elems/lane: sl=lane&31 owns elems
// {4sl..4sl+3}, head = sl>>2; the two half-waves process edges 2i and 2i+1.
// exp via native v_exp_f32: log2(e) folded into the q prescale.
// Divergence-free inner loop; odd-cnt tail is a duplicated edge w/ weight 0.
// q fp32 (may alias t: each node's q row read before its t row written).
// ---------------------------------------------------------------------------
__launch_bounds__(256, 8)
__global__ void fused_attn(const float* __restrict__ q,
                           const unsigned short* __restrict__ kv,
                           const int* __restrict__ offs, const int* __restrict__ sorted_src,
                           const float* __restrict__ rel_pri, float* __restrict__ t) {
    int wave = threadIdx.x >> 6, lane = threadIdx.x & 63;
    int half = lane >> 5;
    int sl = lane & 31;
    int hh = sl >> 2;
    // fold rel_pri/sqrt(dk) AND log2(e) into the q prescale: exp(p)=exp2(p')
    float scale = rel_pri[hh] * 0.25f * 1.44269504088896340736f;
    const unsigned short* kvp = kv + sl * 8;   // lane-fixed sub-offset

    int n0 = (blockIdx.x * 4 + wave) * 4;
    #pragma unroll 1
    for (int ni = 0; ni < 4; ni++) {
        int n = n0 + ni;
        if (n >= NN) return;
        int start = (n > 0) ? offs[n - 1] : 0;
        int cnt = offs[n] - start;

        float4 q4 = *(const float4*)&q[(size_t)n * 128 + sl * 4];
        q4.x *= scale; q4.y *= scale; q4.z *= scale; q4.w *= scale;

        float4 o4 = {0.f, 0.f, 0.f, 0.f};
        float denom = 0.f;

        int nIter = (cnt + 1) >> 1;
        #pragma unroll 4
        for (int it = 0; it < nIter; it++) {
            int j = 2 * it + half;
            float wgt = (j < cnt) ? 1.f : 0.f;
            int jj = (j < cnt) ? j : (cnt - 1);
            int s = sorted_src[start + jj];
            uint4 kvb = *(const uint4*)(kvp + (size_t)s * 256);  // k4 | v4, 16B
            float p = q4.x * bf2f((unsigned short)(kvb.x & 0xffff))
                    + q4.y * bf2f((unsigned short)(kvb.x >> 16))
                    + q4.z * bf2f((unsigned short)(kvb.y & 0xffff))
                    + q4.w * bf2f((unsigned short)(kvb.y >> 16));
            p += __shfl_xor(p, 1);
            p += __shfl_xor(p, 2);
            float e = __builtin_amdgcn_exp2f(p) * wgt;   // native v_exp_f32
            denom += e;
            o4.x = fmaf(bf2f((unsigned short)(kvb.z & 0xffff)), e, o4.x);
            o4.y = fmaf(bf2f((unsigned short)(kvb.z >> 16)),    e, o4.y);
            o4.z = fmaf(bf2f((unsigned short)(kvb.w & 0xffff)), e, o4.z);
            o4.w = fmaf(bf2f((unsigned short)(kvb.w >> 16)),    e, o4.w);
        }

        // combine the two halves (all 64 lanes active)
        denom += __shfl_xor(denom, 32);
        o4.x += __shfl_xor(o4.x, 32);
        o4.y += __shfl_xor(o4.y, 32);
        o4.z += __shfl_xor(o4.z, 32);
        o4.w += __shfl_xor(o4.w, 32);

        if (half == 0) {
            float inv = (cnt > 0) ? 1.f / denom : 0.f;
            o4.x *= inv; o4.y *= inv; o4.z *= inv; o4.w *= inv;
            *(float4*)&t[(size_t)n * 128 + sl * 4] = o4;
        }
    }
}

// ---------------------------------------------------------------------------
extern "C" void kernel_launch(void* const* d_in, const int* in_sizes, int n_in,
                              void* d_out, int out_size, void* d_ws, size_t ws_size,
                              hipStream_t stream) {
    const float* h    = (const float*)d_in[0];
    const int*   src  = (const int*)d_in[1];
    const int*   dst  = (const int*)d_in[2];
    const float* Wk   = (const float*)d_in[3];
    const float* bk   = (const float*)d_in[4];
    const float* Wq   = (const float*)d_in[5];
    const float* bq   = (const float*)d_in[6];
    const float* Wv   = (const float*)d_in[7];
    const float* bv   = (const float*)d_in[8];
    const float* Wa   = (const float*)d_in[9];
    const float* ba   = (const float*)d_in[10];
    const float* rel_att = (const float*)d_in[11];
    const float* rel_msg = (const float*)d_in[12];
    const float* rel_pri = (const float*)d_in[13];
    const float* skip    = (const float*)d_in[14];
    float* out = (float*)d_out;

    unsigned short* kvbuf = (unsigned short*)d_ws;            // N*256 bf16
    float* BE   = (float*)(kvbuf + (size_t)NN * 256);         // 4*128
    int* scratch = (int*)(BE + 512);                          // N ints
    int* bcnt  = scratch;                                     // NB
    int* btail = bcnt + NB;                                   // NB
    int* sbase = btail + NB;                                  // NB+1
    int* offs  = scratch + NN;                                // N
    int* bsum  = offs + NN;                                   // 128 (layout keep)
    int* sorted_src = bsum + 128;                             // E
    unsigned short* WH = (unsigned short*)(sorted_src + EE);  // 4*16384 bf16
    unsigned short* WL = WH + 4 * 16384;                      // 4*16384 bf16
    char* ws_end = (char*)(WL + 4 * 16384);
    size_t used = (size_t)(ws_end - (char*)d_ws);
    // packed edges: dedicated region if workspace allows (enables
    // gemm0 || scatter overlap); else alias kvbuf (serial fallback).
    bool sep = (ws_size >= used + (size_t)EE * sizeof(int));
    int* packed = sep ? (int*)ws_end : (int*)kvbuf;
    float* q = out;                                // q lives in d_out; t aliases q
    float* t = out;

    hipMemsetAsync(bcnt, 0, NB * sizeof(int), stream);
    // prep_weights || bucket_hist in one dispatch
    prep_hist<<<256 + A_BLOCKS, 256, 0, stream>>>(Wq, Wk, Wv, Wa, bq, bk, bv, ba,
                                                  rel_att, rel_msg, WH, WL, BE,
                                                  dst, bcnt);
    bucket_scan<<<1, 256, 0, stream>>>(bcnt, btail, sbase);

    if (sep) {
        // qkv GEMM || bucket scatter (disjoint memory), then node_sort
        gemm0_scatter<<<A_BLOCKS + GEMM_BLOCKS, 256, 0, stream>>>(
            h, WH, WL, BE, q, kvbuf, src, dst, btail, packed);
        node_sort<<<NB, 512, 0, stream>>>(packed, sbase, offs, sorted_src);
    } else {
        // serial fallback: packed aliases kvbuf, must finish CSR before gemm0
        bucket_scatter<<<A_BLOCKS, 256, 0, stream>>>(src, dst, btail, packed);
        node_sort<<<NB, 512, 0, stream>>>(packed, sbase, offs, sorted_src);
        gemm_reg<<<GEMM_BLOCKS, 256, 0, stream>>>(h, WH, WL, BE, 3, q, kvbuf,
                                                  nullptr, nullptr);
    }

    // fused single-pass attention (no atomics)
    fused_attn<<<(NN + 15) / 16, 256, 0, stream>>>(q, kvbuf, offs, sorted_src,
                                                   rel_pri, t);
    // final projection + skip-gate mix (in-place on d_out)
    gemm_reg<<<GEMM_BLOCKS, 256, 0, stream>>>(t, WH + 3 * 16384, WL + 3 * 16384,
                                              BE + 384, 1, out, nullptr,
                                              h, skip);
}

// Round 5
// 481.891 us; speedup vs baseline: 1.0268x; 1.0236x over previous
//
#include <hip/hip_runtime.h>
#include <hip/hip_bf16.h>
#include <math.h>

#define NN 100000
#define EE 1600000
#define DD 128
#define HH 8
#define LDW 136   // padded LDS row stride (bf16 elems) for 128-wide W tiles
#define BSH 9     // bucket shift: 512 nodes per bucket
#define NB 196    // ceil(NN / 512)
#define EPB 8192  // edges per block in bucket pass A
#define A_BLOCKS 196   // (EE + EPB - 1) / EPB
#define GEMM_BLOCKS 782  // (NN + 127) / 128

typedef short short8 __attribute__((ext_vector_type(8)));
typedef float f32x4 __attribute__((ext_vector_type(4)));

__device__ __forceinline__ unsigned short f2bf(float f) {  // RNE float->bf16 bits
    unsigned int u = __float_as_uint(f);
    u += 0x7fffu + ((u >> 16) & 1u);
    return (unsigned short)(u >> 16);
}
__device__ __forceinline__ float bf2f(unsigned short h) {
    return __uint_as_float((unsigned int)h << 16);
}
// 8 floats -> bf16 hi + residual-lo vectors
__device__ __forceinline__ void cvt8(const float4& a, const float4& b,
                                     short8& h8, short8& l8) {
    float vals[8] = {a.x, a.y, a.z, a.w, b.x, b.y, b.z, b.w};
    #pragma unroll
    for (int j = 0; j < 8; j++) {
        unsigned short hi = f2bf(vals[j]);
        h8[j] = (short)hi;
        l8[j] = (short)f2bf(vals[j] - bf2f(hi));
    }
}

// ---------------------------------------------------------------------------
// prep_weights body: fold rel_att/rel_msg into Wk/Wv; emit all 4 weights in
// [j][c] order as bf16 hi/lo pairs + effective biases. which: 0=q,1=k,2=v,3=a
// ---------------------------------------------------------------------------
__device__ __forceinline__ void prep_work(int which, int bx,
                             const float* __restrict__ Wq, const float* __restrict__ Wk,
                             const float* __restrict__ Wv, const float* __restrict__ Wa,
                             const float* __restrict__ bq, const float* __restrict__ bk,
                             const float* __restrict__ bv, const float* __restrict__ ba,
                             const float* __restrict__ rel_att, const float* __restrict__ rel_msg,
                             unsigned short* __restrict__ WH, unsigned short* __restrict__ WL,
                             float* __restrict__ BE) {
    int o = bx * 256 + threadIdx.x;   // [j][c], j=out col, c=in dim
    int j = o >> 7, c = o & 127;
    float val;
    if (which == 0) {
        val = Wq[o];
        if (o < 128) BE[o] = bq[o];
    } else if (which == 3) {
        val = Wa[o];
        if (o < 128) BE[384 + o] = ba[o];
    } else {
        const float* rel = (which == 1) ? rel_att : rel_msg;
        const float* W   = (which == 1) ? Wk : Wv;
        const float* b   = (which == 1) ? bk : bv;
        int hh = j >> 4, e = j & 15;
        val = 0.f;
        #pragma unroll
        for (int d = 0; d < 16; d++)
            val += rel[hh * 256 + d * 16 + e] * W[(hh * 16 + d) * 128 + c];
        if (c == 0) {
            float bacc = 0.f;
            #pragma unroll
            for (int d = 0; d < 16; d++)
                bacc += b[hh * 16 + d] * rel[hh * 256 + d * 16 + e];
            BE[which * 128 + j] = bacc;
        }
    }
    unsigned short hi = f2bf(val);
    unsigned short lo = f2bf(val - bf2f(hi));
    WH[which * 16384 + o] = hi;
    WL[which * 16384 + o] = lo;
}

// fused: blocks [0,256) do prep_weights (which = bid>>6), blocks [256,256+196)
// do the bucket histogram. Independent work, overlapped in one dispatch.
__global__ void prep_hist(const float* __restrict__ Wq, const float* __restrict__ Wk,
                          const float* __restrict__ Wv, const float* __restrict__ Wa,
                          const float* __restrict__ bq, const float* __restrict__ bk,
                          const float* __restrict__ bv, const float* __restrict__ ba,
                          const float* __restrict__ rel_att, const float* __restrict__ rel_msg,
                          unsigned short* __restrict__ WH, unsigned short* __restrict__ WL,
                          float* __restrict__ BE,
                          const int* __restrict__ dst, int* __restrict__ bcnt) {
    __shared__ int lh[NB];
    int bid = blockIdx.x;
    if (bid < 256) {
        prep_work(bid >> 6, bid & 63, Wq, Wk, Wv, Wa, bq, bk, bv, ba,
                  rel_att, rel_msg, WH, WL, BE);
    } else {
        int t = threadIdx.x;
        for (int i = t; i < NB; i += 256) lh[i] = 0;
        __syncthreads();
        int base = (bid - 256) * EPB;
        int cnt = min(EPB, EE - base);
        for (int i = t; i < cnt; i += 256)
            atomicAdd(&lh[dst[base + i] >> BSH], 1);
        __syncthreads();
        for (int i = t; i < NB; i += 256)
            if (lh[i]) atomicAdd(&bcnt[i], lh[i]);
    }
}

// ---------------------------------------------------------------------------
// Register-A MFMA GEMM body, bf16 hi/lo split (R6-proven). In-place safe.
// kv output layout (wi=1,2): interleaved per 4-elem group so fused_attn can
// read each lane's k4+v4 with ONE dwordx4:
//   kv[row][ (col>>2)*8 + (wi-1)*4 + (col&3) ]
// smemc: >= 69632 bytes, 16B-aligned.
// ---------------------------------------------------------------------------
__device__ __forceinline__ void gemm_body(char* smemc, int base,
                         const float* __restrict__ x,
                         const unsigned short* __restrict__ WH,
                         const unsigned short* __restrict__ WL,
                         const float* __restrict__ BE, int nw,
                         float* __restrict__ out0, unsigned short* __restrict__ kvout,
                         const float* __restrict__ resid, const float* __restrict__ skip) {
    unsigned short* wh = (unsigned short*)smemc;           // 128*LDW
    unsigned short* wl = wh + 128 * LDW;                   // 128*LDW
    int tid = threadIdx.x;
    int wv = tid >> 6, lane = tid & 63;
    int lrow = lane & 15, quad = lane >> 4;

    // ---- load this wave's 32 x-rows into A-fragment registers (hi/lo) ----
    short8 ah[2][4], al[2][4];
    float4 fz = {0.f, 0.f, 0.f, 0.f};
    #pragma unroll
    for (int mt = 0; mt < 2; mt++) {
        int row = base + wv * 32 + mt * 16 + lrow;
        const float* xr = x + (size_t)row * 128;
        bool ok = (row < NN);
        #pragma unroll
        for (int kc = 0; kc < 4; kc++) {
            int off = kc * 32 + quad * 8;
            float4 a = ok ? *(const float4*)&xr[off] : fz;
            float4 b = ok ? *(const float4*)&xr[off + 4] : fz;
            cvt8(a, b, ah[mt][kc], al[mt][kc]);
        }
    }

    float alpha = 1.f, beta = 0.f;
    if (resid) {
        float sv = skip[0];
        alpha = 1.f / (1.f + expf(-sv));
        beta = 1.f - alpha;
    }

    for (int wi = 0; wi < nw; wi++) {
        __syncthreads();   // prior-phase W readers done
        const unsigned short* WHp = WH + wi * 16384;
        const unsigned short* WLp = WL + wi * 16384;
        for (int i = tid; i < 128 * 16; i += 256) {
            int n = i >> 4, kq = (i & 15) << 3;
            *(uint4*)&wh[n * LDW + kq] = *(const uint4*)&WHp[n * 128 + kq];
            *(uint4*)&wl[n * LDW + kq] = *(const uint4*)&WLp[n * 128 + kq];
        }
        __syncthreads();

        f32x4 zero4 = {0.f, 0.f, 0.f, 0.f};
        f32x4 acc[2][8];
        #pragma unroll
        for (int a = 0; a < 2; a++)
            #pragma unroll
            for (int b = 0; b < 8; b++) acc[a][b] = zero4;

        #pragma unroll
        for (int kc = 0; kc < 4; kc++) {
            #pragma unroll
            for (int nt = 0; nt < 8; nt++) {
                int koff = kc * 32 + quad * 8;
                int brow = (nt * 16 + lrow) * LDW + koff;
                short8 bh = *(const short8*)&wh[brow];
                short8 bl = *(const short8*)&wl[brow];
                acc[0][nt] = __builtin_amdgcn_mfma_f32_16x16x32_bf16(ah[0][kc], bh, acc[0][nt], 0, 0, 0);
                acc[1][nt] = __builtin_amdgcn_mfma_f32_16x16x32_bf16(ah[1][kc], bh, acc[1][nt], 0, 0, 0);
                acc[0][nt] = __builtin_amdgcn_mfma_f32_16x16x32_bf16(al[0][kc], bh, acc[0][nt], 0, 0, 0);
                acc[1][nt] = __builtin_amdgcn_mfma_f32_16x16x32_bf16(al[1][kc], bh, acc[1][nt], 0, 0, 0);
                acc[0][nt] = __builtin_amdgcn_mfma_f32_16x16x32_bf16(ah[0][kc], bl, acc[0][nt], 0, 0, 0);
                acc[1][nt] = __builtin_amdgcn_mfma_f32_16x16x32_bf16(ah[1][kc], bl, acc[1][nt], 0, 0, 0);
            }
        }

        const float* be = BE + wi * 128;
        #pragma unroll
        for (int nt = 0; nt < 8; nt++) {
            int col = nt * 16 + lrow;
            float bb = be[col];
            #pragma unroll
            for (int mt = 0; mt < 2; mt++) {
                int r0 = base + wv * 32 + mt * 16 + quad * 4;
                #pragma unroll
                for (int rg = 0; rg < 4; rg++) {
                    int row = r0 + rg;
                    if (row < NN) {
                        float val = acc[mt][nt][rg] + bb;
                        if (wi == 0) {
                            if (resid) val = alpha * val + beta * resid[(size_t)row * 128 + col];
                            out0[(size_t)row * 128 + col] = val;
                        } else {
                            int pos = ((col >> 2) << 3) + ((wi - 1) << 2) + (col & 3);
                            kvout[(size_t)row * 256 + pos] = f2bf(val);
                        }
                    }
                }
            }
        }
    }
}

__launch_bounds__(256, 2)
__global__ void gemm_reg(const float* __restrict__ x,
                         const unsigned short* __restrict__ WH,
                         const unsigned short* __restrict__ WL,
                         const float* __restrict__ BE, int nw,
                         float* __restrict__ out0, unsigned short* __restrict__ kvout,
                         const float* __restrict__ resid, const float* __restrict__ skip) {
    __shared__ __align__(16) char smem[69632];
    gemm_body(smem, blockIdx.x * 128, x, WH, WL, BE, nw, out0, kvout, resid, skip);
}

// ======================= CSR build: 2-pass bucket sort =====================
// exclusive scan of bcnt[NB] -> btail (running cursors) + sbase (fixed bases)
__global__ void bucket_scan(const int* __restrict__ bcnt, int* __restrict__ btail,
                            int* __restrict__ sbase) {
    __shared__ int buf[2][256];
    int t = threadIdx.x;
    int v = (t < NB) ? bcnt[t] : 0;
    buf[0][t] = v;
    __syncthreads();
    int sb = 0;
    #pragma unroll
    for (int d = 1; d < 256; d <<= 1) {
        int x = buf[sb][t];
        if (t >= d) x += buf[sb][t - d];
        buf[sb ^ 1][t] = x;
        __syncthreads();
        sb ^= 1;
    }
    if (t < NB) {
        int excl = buf[sb][t] - v;
        btail[t] = excl;
        sbase[t] = excl;
    }
    if (t == 0) sbase[NB] = EE;
}

// scatter body. smemc layout (70720B total, 16B-aligned):
//   staged int2[8192] @0 (64KB) | hist[NB] | lstart[NB] | cursor[NB] |
//   gbase[NB] | sbuf[2][256]
__device__ __forceinline__ void scatter_work(char* smemc, int bid,
                               const int* __restrict__ src, const int* __restrict__ dst,
                               int* __restrict__ btail, int* __restrict__ packed) {
    int2* staged = (int2*)smemc;
    int* hist   = (int*)(smemc + 65536);
    int* lstart = hist + NB;
    int* cursor = lstart + NB;
    int* gbase  = cursor + NB;
    int* sbuf   = gbase + NB;   // [2][256]
    int t = threadIdx.x;
    for (int i = t; i < NB; i += 256) hist[i] = 0;
    __syncthreads();
    int base = bid * EPB;
    int cnt = min(EPB, EE - base);
    for (int i = t; i < cnt; i += 256)
        atomicAdd(&hist[dst[base + i] >> BSH], 1);
    __syncthreads();
    // exclusive scan of hist -> lstart, init cursor
    int v = (t < NB) ? hist[t] : 0;
    sbuf[t] = v;
    __syncthreads();
    int sb = 0;
    #pragma unroll
    for (int d = 1; d < 256; d <<= 1) {
        int x = sbuf[sb * 256 + t];
        if (t >= d) x += sbuf[sb * 256 + t - d];
        sbuf[(sb ^ 1) * 256 + t] = x;
        __syncthreads();
        sb ^= 1;
    }
    if (t < NB) {
        lstart[t] = sbuf[sb * 256 + t] - v;
        cursor[t] = sbuf[sb * 256 + t] - v;
    }
    __syncthreads();
    // rank + stage (re-read edges; L2-hot)
    for (int i = t; i < cnt; i += 256) {
        int d = dst[base + i], s = src[base + i];
        int r = atomicAdd(&cursor[d >> BSH], 1);
        staged[r] = make_int2(s, d);
    }
    // reserve global runs
    __syncthreads();
    for (int i = t; i < NB; i += 256) {
        int c = hist[i];
        if (c) gbase[i] = atomicAdd(&btail[i], c);
    }
    __syncthreads();
    // coalesced run writes
    for (int i = t; i < cnt; i += 256) {
        int2 e = staged[i];
        int b = e.y >> BSH;
        packed[gbase[b] + (i - lstart[b])] = ((e.y & 511) << 17) | e.x;
    }
}

__launch_bounds__(256, 1)
__global__ void bucket_scatter(const int* __restrict__ src, const int* __restrict__ dst,
                               int* __restrict__ btail, int* __restrict__ packed) {
    __shared__ __align__(16) char smem[70720];
    scatter_work(smem, blockIdx.x, src, dst, btail, packed);
}

// fused: blocks [0,196) run bucket_scatter (critical path to node_sort),
// blocks [196, 196+782) run the 3-way qkv GEMM. Independent (packed is
// disjoint from kvbuf in this path). Union LDS 70720B -> 2 blocks/CU.
__launch_bounds__(256, 2)
__global__ void gemm0_scatter(const float* __restrict__ x,
                              const unsigned short* __restrict__ WH,
                              const unsigned short* __restrict__ WL,
                              const float* __restrict__ BE,
                              float* __restrict__ q, unsigned short* __restrict__ kvout,
                              const int* __restrict__ src, const int* __restrict__ dst,
                              int* __restrict__ btail, int* __restrict__ packed) {
    __shared__ __align__(16) char smem[70720];
    if (blockIdx.x < A_BLOCKS)
        scatter_work(smem, blockIdx.x, src, dst, btail, packed);
    else
        gemm_body(smem, (blockIdx.x - A_BLOCKS) * 128, x, WH, WL, BE, 3,
                  q, kvout, nullptr, nullptr);
}

__launch_bounds__(512, 2)
__global__ void node_sort(const int* __restrict__ packed, const int* __restrict__ sbase,
                          int* __restrict__ offs, int* __restrict__ sorted_src) {
    __shared__ int hist[512], cursor[512];
    __shared__ int scn[2][512];
    int t = threadIdx.x;
    int b = blockIdx.x;
    int s0 = sbase[b], s1 = sbase[b + 1];
    hist[t] = 0;
    __syncthreads();
    for (int e = s0 + t; e < s1; e += 512)
        atomicAdd(&hist[packed[e] >> 17], 1);
    __syncthreads();
    int v = hist[t];
    scn[0][t] = v;
    __syncthreads();
    int sb = 0;
    #pragma unroll
    for (int d = 1; d < 512; d <<= 1) {
        int x = scn[sb][t];
        if (t >= d) x += scn[sb][t - d];
        scn[sb ^ 1][t] = x;
        __syncthreads();
        sb ^= 1;
    }
    int incl = scn[sb][t];
    int node = (b << BSH) + t;
    if (node < NN) offs[node] = s0 + incl;    // inclusive end, CSR semantics
    cursor[t] = s0 + incl - v;                // exclusive start
    __syncthreads();
    for (int e = s0 + t; e < s1; e += 512) {
        int p = packed[e];
        int pos = atomicAdd(&cursor[p >> 17], 1);
        sorted_src[pos] = p & 0x1FFFF;        // writes confined to 32KB window
    }
}

// ---------------------------------------------------------------------------
// Fused per-dst attention, single pass, bf16 packed interleaved kv[n][256]:
// group g (=sl) holds {k[4g..4g+3], v[4g..4g+3]} at byte offset g*16 -> one
// dwordx4 per lane per edge (512B contiguous per half-wave request).
// One wave per node (R2-proven best: 1 node/wave beats 4 nodes/wave by 14us;
// occupancy 4 vs 8 wg/CU indistinguishable -- gather-service-rate bound).
// 4 elems/lane: sl=lane&31 owns elems {4sl..4sl+3}, head = sl>>2; the two
// half-waves process edges 2i and 2i+1.
// exp via native v_exp_f32: log2(e) folded into the q prescale.
// Divergence-free: all 64 lanes active every iteration; odd-cnt tail is a
// duplicated edge with weight 0. q fp32 (may alias t: read before write).
// ---------------------------------------------------------------------------
__launch_bounds__(256, 4)
__global__ void fused_attn(const float* __restrict__ q,
                           const unsigned short* __restrict__ kv,
                           const int* __restrict__ offs, const int* __restrict__ sorted_src,
                           const float* __restrict__ rel_pri, float* __restrict__ t) {
    int wave = threadIdx.x >> 6, lane = threadIdx.x & 63;
    int n = blockIdx.x * 4 + wave;
    if (n >= NN) return;
    int half = lane >> 5;
    int sl = lane & 31;
    int hh = sl >> 2;
    int start = (n > 0) ? offs[n - 1] : 0;
    int cnt = offs[n] - start;

    float4 q4 = *(const float4*)&q[(size_t)n * 128 + sl * 4];
    // fold rel_pri/sqrt(dk) AND log2(e) into the q prescale: exp(p)=exp2(p')
    float scale = rel_pri[hh] * 0.25f * 1.44269504088896340736f;
    q4.x *= scale; q4.y *= scale; q4.z *= scale; q4.w *= scale;

    const unsigned short* kvp = kv + sl * 8;   // lane-fixed sub-offset

    float4 o4 = {0.f, 0.f, 0.f, 0.f};
    float denom = 0.f;

    int nIter = (cnt + 1) >> 1;
    #pragma unroll 4
    for (int it = 0; it < nIter; it++) {
        int j = 2 * it + half;
        float wgt = (j < cnt) ? 1.f : 0.f;
        int jj = (j < cnt) ? j : (cnt - 1);
        int s = sorted_src[start + jj];
        uint4 kvb = *(const uint4*)(kvp + (size_t)s * 256);  // k4 | v4, 16B
        float p = q4.x * bf2f((unsigned short)(kvb.x & 0xffff))
                + q4.y * bf2f((unsigned short)(kvb.x >> 16))
                + q4.z * bf2f((unsigned short)(kvb.y & 0xffff))
                + q4.w * bf2f((unsigned short)(kvb.y >> 16));
        p += __shfl_xor(p, 1);
        p += __shfl_xor(p, 2);
        float e = __builtin_amdgcn_exp2f(p) * wgt;   // native v_exp_f32
        denom += e;
        o4.x = fmaf(bf2f((unsigned short)(kvb.z & 0xffff)), e, o4.x);
        o4.y = fmaf(bf2f((unsigned short)(kvb.z >> 16)),    e, o4.y);
        o4.z = fmaf(bf2f((unsigned short)(kvb.w & 0xffff)), e, o4.z);
        o4.w = fmaf(bf2f((unsigned short)(kvb.w >> 16)),    e, o4.w);
    }

    // combine the two halves (all 64 lanes active)
    denom += __shfl_xor(denom, 32);
    o4.x += __shfl_xor(o4.x, 32);
    o4.y += __shfl_xor(o4.y, 32);
    o4.z += __shfl_xor(o4.z, 32);
    o4.w += __shfl_xor(o4.w, 32);

    if (half == 0) {
        float inv = (cnt > 0) ? 1.f / denom : 0.f;
        o4.x *= inv; o4.y *= inv; o4.z *= inv; o4.w *= inv;
        *(float4*)&t[(size_t)n * 128 + sl * 4] = o4;
    }
}

// ---------------------------------------------------------------------------
extern "C" void kernel_launch(void* const* d_in, const int* in_sizes, int n_in,
                              void* d_out, int out_size, void* d_ws, size_t ws_size,
                              hipStream_t stream) {
    const float* h    = (const float*)d_in[0];
    const int*   src  = (const int*)d_in[1];
    const int*   dst  = (const int*)d_in[2];
    const float* Wk   = (const float*)d_in[3];
    const float* bk   = (const float*)d_in[4];
    const float* Wq   = (const float*)d_in[5];
    const float* bq   = (const float*)d_in[6];
    const float* Wv   = (const float*)d_in[7];
    const float* bv   = (const float*)d_in[8];
    const float* Wa   = (const float*)d_in[9];
    const float* ba   = (const float*)d_in[10];
    const float* rel_att = (const float*)d_in[11];
    const float* rel_msg = (const float*)d_in[12];
    const float* rel_pri = (const float*)d_in[13];
    const float* skip    = (const float*)d_in[14];
    float* out = (float*)d_out;

    unsigned short* kvbuf = (unsigned short*)d_ws;            // N*256 bf16
    float* BE   = (float*)(kvbuf + (size_t)NN * 256);         // 4*128
    int* scratch = (int*)(BE + 512);                          // N ints
    int* bcnt  = scratch;                                     // NB
    int* btail = bcnt + NB;                                   // NB
    int* sbase = btail + NB;                                  // NB+1
    int* offs  = scratch + NN;                                // N
    int* bsum  = offs + NN;                                   // 128 (layout keep)
    int* sorted_src = bsum + 128;                             // E
    unsigned short* WH = (unsigned short*)(sorted_src + EE);  // 4*16384 bf16
    unsigned short* WL = WH + 4 * 16384;                      // 4*16384 bf16
    char* ws_end = (char*)(WL + 4 * 16384);
    size_t used = (size_t)(ws_end - (char*)d_ws);
    // packed edges: dedicated region if workspace allows (enables
    // gemm0 || scatter overlap); else alias kvbuf (serial fallback).
    bool sep = (ws_size >= used + (size_t)EE * sizeof(int));
    int* packed = sep ? (int*)ws_end : (int*)kvbuf;
    float* q = out;                                // q lives in d_out; t aliases q
    float* t = out;

    hipMemsetAsync(bcnt, 0, NB * sizeof(int), stream);
    // prep_weights || bucket_hist in one dispatch
    prep_hist<<<256 + A_BLOCKS, 256, 0, stream>>>(Wq, Wk, Wv, Wa, bq, bk, bv, ba,
                                                  rel_att, rel_msg, WH, WL, BE,
                                                  dst, bcnt);
    bucket_scan<<<1, 256, 0, stream>>>(bcnt, btail, sbase);

    if (sep) {
        // qkv GEMM || bucket scatter (disjoint memory), then node_sort
        gemm0_scatter<<<A_BLOCKS + GEMM_BLOCKS, 256, 0, stream>>>(
            h, WH, WL, BE, q, kvbuf, src, dst, btail, packed);
        node_sort<<<NB, 512, 0, stream>>>(packed, sbase, offs, sorted_src);
    } else {
        // serial fallback: packed aliases kvbuf, must finish CSR before gemm0
        bucket_scatter<<<A_BLOCKS, 256, 0, stream>>>(src, dst, btail, packed);
        node_sort<<<NB, 512, 0, stream>>>(packed, sbase, offs, sorted_src);
        gemm_reg<<<GEMM_BLOCKS, 256, 0, stream>>>(h, WH, WL, BE, 3, q, kvbuf,
                                                  nullptr, nullptr);
    }

    // fused single-pass attention (no atomics)
    fused_attn<<<(NN + 3) / 4, 256, 0, stream>>>(q, kvbuf, offs, sorted_src,
                                                 rel_pri, t);
    // final projection + skip-gate mix (in-place on d_out)
    gemm_reg<<<GEMM_BLOCKS, 256, 0, stream>>>(t, WH + 3 * 16384, WL + 3 * 16384,
                                              BE + 384, 1, out, nullptr,
                                              h, skip);
}

// Round 6
// 476.398 us; speedup vs baseline: 1.0386x; 1.0115x over previous
//
#include <hip/hip_runtime.h>
#include <hip/hip_bf16.h>
#include <math.h>

#define NN 100000
#define EE 1600000
#define DD 128
#define HH 8
#define LDW 136   // padded LDS row stride (bf16 elems) for 128-wide W tiles
#define BSH 9     // bucket shift: 512 nodes per bucket
#define NB 196    // ceil(NN / 512)
#define EPB 8192  // edges per block in bucket pass A
#define A_BLOCKS 196   // (EE + EPB - 1) / EPB
#define GEMM_BLOCKS 782  // (NN + 127) / 128
#define G1 316    // gemm blocks in dispatch D1: 196 + 316 = 512 = one full batch

typedef short short8 __attribute__((ext_vector_type(8)));
typedef float f32x4 __attribute__((ext_vector_type(4)));

__device__ __forceinline__ unsigned short f2bf(float f) {  // RNE float->bf16 bits
    unsigned int u = __float_as_uint(f);
    u += 0x7fffu + ((u >> 16) & 1u);
    return (unsigned short)(u >> 16);
}
__device__ __forceinline__ float bf2f(unsigned short h) {
    return __uint_as_float((unsigned int)h << 16);
}
// 8 floats -> bf16 hi + residual-lo vectors
__device__ __forceinline__ void cvt8(const float4& a, const float4& b,
                                     short8& h8, short8& l8) {
    float vals[8] = {a.x, a.y, a.z, a.w, b.x, b.y, b.z, b.w};
    #pragma unroll
    for (int j = 0; j < 8; j++) {
        unsigned short hi = f2bf(vals[j]);
        h8[j] = (short)hi;
        l8[j] = (short)f2bf(vals[j] - bf2f(hi));
    }
}

// ---------------------------------------------------------------------------
// prep_weights body: fold rel_att/rel_msg into Wk/Wv; emit all 4 weights in
// [j][c] order as bf16 hi/lo pairs + effective biases. which: 0=q,1=k,2=v,3=a
// ---------------------------------------------------------------------------
__device__ __forceinline__ void prep_work(int which, int bx,
                             const float* __restrict__ Wq, const float* __restrict__ Wk,
                             const float* __restrict__ Wv, const float* __restrict__ Wa,
                             const float* __restrict__ bq, const float* __restrict__ bk,
                             const float* __restrict__ bv, const float* __restrict__ ba,
                             const float* __restrict__ rel_att, const float* __restrict__ rel_msg,
                             unsigned short* __restrict__ WH, unsigned short* __restrict__ WL,
                             float* __restrict__ BE) {
    int o = bx * 256 + threadIdx.x;   // [j][c], j=out col, c=in dim
    int j = o >> 7, c = o & 127;
    float val;
    if (which == 0) {
        val = Wq[o];
        if (o < 128) BE[o] = bq[o];
    } else if (which == 3) {
        val = Wa[o];
        if (o < 128) BE[384 + o] = ba[o];
    } else {
        const float* rel = (which == 1) ? rel_att : rel_msg;
        const float* W   = (which == 1) ? Wk : Wv;
        const float* b   = (which == 1) ? bk : bv;
        int hh = j >> 4, e = j & 15;
        val = 0.f;
        #pragma unroll
        for (int d = 0; d < 16; d++)
            val += rel[hh * 256 + d * 16 + e] * W[(hh * 16 + d) * 128 + c];
        if (c == 0) {
            float bacc = 0.f;
            #pragma unroll
            for (int d = 0; d < 16; d++)
                bacc += b[hh * 16 + d] * rel[hh * 256 + d * 16 + e];
            BE[which * 128 + j] = bacc;
        }
    }
    unsigned short hi = f2bf(val);
    unsigned short lo = f2bf(val - bf2f(hi));
    WH[which * 16384 + o] = hi;
    WL[which * 16384 + o] = lo;
}

// fused: blocks [0,256) do prep_weights (which = bid>>6), blocks [256,256+196)
// do the bucket histogram. Independent work, overlapped in one dispatch.
__global__ void prep_hist(const float* __restrict__ Wq, const float* __restrict__ Wk,
                          const float* __restrict__ Wv, const float* __restrict__ Wa,
                          const float* __restrict__ bq, const float* __restrict__ bk,
                          const float* __restrict__ bv, const float* __restrict__ ba,
                          const float* __restrict__ rel_att, const float* __restrict__ rel_msg,
                          unsigned short* __restrict__ WH, unsigned short* __restrict__ WL,
                          float* __restrict__ BE,
                          const int* __restrict__ dst, int* __restrict__ bcnt) {
    __shared__ int lh[NB];
    int bid = blockIdx.x;
    if (bid < 256) {
        prep_work(bid >> 6, bid & 63, Wq, Wk, Wv, Wa, bq, bk, bv, ba,
                  rel_att, rel_msg, WH, WL, BE);
    } else {
        int t = threadIdx.x;
        for (int i = t; i < NB; i += 256) lh[i] = 0;
        __syncthreads();
        int base = (bid - 256) * EPB;
        int cnt = min(EPB, EE - base);
        for (int i = t; i < cnt; i += 256)
            atomicAdd(&lh[dst[base + i] >> BSH], 1);
        __syncthreads();
        for (int i = t; i < NB; i += 256)
            if (lh[i]) atomicAdd(&bcnt[i], lh[i]);
    }
}

// ---------------------------------------------------------------------------
// Register-A MFMA GEMM body, bf16 hi/lo split (R6-proven). In-place safe.
// kv output layout (wi=1,2): interleaved per 4-elem group so fused_attn can
// read each lane's k4+v4 with ONE dwordx4:
//   kv[row][ (col>>2)*8 + (wi-1)*4 + (col&3) ]
// smemc: >= 69632 bytes, 16B-aligned.
// ---------------------------------------------------------------------------
__device__ __forceinline__ void gemm_body(char* smemc, int base,
                         const float* __restrict__ x,
                         const unsigned short* __restrict__ WH,
                         const unsigned short* __restrict__ WL,
                         const float* __restrict__ BE, int nw,
                         float* __restrict__ out0, unsigned short* __restrict__ kvout,
                         const float* __restrict__ resid, const float* __restrict__ skip) {
    unsigned short* wh = (unsigned short*)smemc;           // 128*LDW
    unsigned short* wl = wh + 128 * LDW;                   // 128*LDW
    int tid = threadIdx.x;
    int wv = tid >> 6, lane = tid & 63;
    int lrow = lane & 15, quad = lane >> 4;

    // ---- load this wave's 32 x-rows into A-fragment registers (hi/lo) ----
    short8 ah[2][4], al[2][4];
    float4 fz = {0.f, 0.f, 0.f, 0.f};
    #pragma unroll
    for (int mt = 0; mt < 2; mt++) {
        int row = base + wv * 32 + mt * 16 + lrow;
        const float* xr = x + (size_t)row * 128;
        bool ok = (row < NN);
        #pragma unroll
        for (int kc = 0; kc < 4; kc++) {
            int off = kc * 32 + quad * 8;
            float4 a = ok ? *(const float4*)&xr[off] : fz;
            float4 b = ok ? *(const float4*)&xr[off + 4] : fz;
            cvt8(a, b, ah[mt][kc], al[mt][kc]);
        }
    }

    float alpha = 1.f, beta = 0.f;
    if (resid) {
        float sv = skip[0];
        alpha = 1.f / (1.f + expf(-sv));
        beta = 1.f - alpha;
    }

    for (int wi = 0; wi < nw; wi++) {
        __syncthreads();   // prior-phase W readers done
        const unsigned short* WHp = WH + wi * 16384;
        const unsigned short* WLp = WL + wi * 16384;
        for (int i = tid; i < 128 * 16; i += 256) {
            int n = i >> 4, kq = (i & 15) << 3;
            *(uint4*)&wh[n * LDW + kq] = *(const uint4*)&WHp[n * 128 + kq];
            *(uint4*)&wl[n * LDW + kq] = *(const uint4*)&WLp[n * 128 + kq];
        }
        __syncthreads();

        f32x4 zero4 = {0.f, 0.f, 0.f, 0.f};
        f32x4 acc[2][8];
        #pragma unroll
        for (int a = 0; a < 2; a++)
            #pragma unroll
            for (int b = 0; b < 8; b++) acc[a][b] = zero4;

        #pragma unroll
        for (int kc = 0; kc < 4; kc++) {
            #pragma unroll
            for (int nt = 0; nt < 8; nt++) {
                int koff = kc * 32 + quad * 8;
                int brow = (nt * 16 + lrow) * LDW + koff;
                short8 bh = *(const short8*)&wh[brow];
                short8 bl = *(const short8*)&wl[brow];
                acc[0][nt] = __builtin_amdgcn_mfma_f32_16x16x32_bf16(ah[0][kc], bh, acc[0][nt], 0, 0, 0);
                acc[1][nt] = __builtin_amdgcn_mfma_f32_16x16x32_bf16(ah[1][kc], bh, acc[1][nt], 0, 0, 0);
                acc[0][nt] = __builtin_amdgcn_mfma_f32_16x16x32_bf16(al[0][kc], bh, acc[0][nt], 0, 0, 0);
                acc[1][nt] = __builtin_amdgcn_mfma_f32_16x16x32_bf16(al[1][kc], bh, acc[1][nt], 0, 0, 0);
                acc[0][nt] = __builtin_amdgcn_mfma_f32_16x16x32_bf16(ah[0][kc], bl, acc[0][nt], 0, 0, 0);
                acc[1][nt] = __builtin_amdgcn_mfma_f32_16x16x32_bf16(ah[1][kc], bl, acc[1][nt], 0, 0, 0);
            }
        }

        const float* be = BE + wi * 128;
        #pragma unroll
        for (int nt = 0; nt < 8; nt++) {
            int col = nt * 16 + lrow;
            float bb = be[col];
            #pragma unroll
            for (int mt = 0; mt < 2; mt++) {
                int r0 = base + wv * 32 + mt * 16 + quad * 4;
                #pragma unroll
                for (int rg = 0; rg < 4; rg++) {
                    int row = r0 + rg;
                    if (row < NN) {
                        float val = acc[mt][nt][rg] + bb;
                        if (wi == 0) {
                            if (resid) val = alpha * val + beta * resid[(size_t)row * 128 + col];
                            out0[(size_t)row * 128 + col] = val;
                        } else {
                            int pos = ((col >> 2) << 3) + ((wi - 1) << 2) + (col & 3);
                            kvout[(size_t)row * 256 + pos] = f2bf(val);
                        }
                    }
                }
            }
        }
    }
}

__launch_bounds__(256, 2)
__global__ void gemm_reg(const float* __restrict__ x,
                         const unsigned short* __restrict__ WH,
                         const unsigned short* __restrict__ WL,
                         const float* __restrict__ BE, int nw,
                         float* __restrict__ out0, unsigned short* __restrict__ kvout,
                         const float* __restrict__ resid, const float* __restrict__ skip) {
    __shared__ __align__(16) char smem[69632];
    gemm_body(smem, blockIdx.x * 128, x, WH, WL, BE, nw, out0, kvout, resid, skip);
}

// ======================= CSR build: 2-pass bucket sort =====================
// exclusive scan of bcnt[NB] -> btail (running cursors) + sbase (fixed bases)
__global__ void bucket_scan(const int* __restrict__ bcnt, int* __restrict__ btail,
                            int* __restrict__ sbase) {
    __shared__ int buf[2][256];
    int t = threadIdx.x;
    int v = (t < NB) ? bcnt[t] : 0;
    buf[0][t] = v;
    __syncthreads();
    int sb = 0;
    #pragma unroll
    for (int d = 1; d < 256; d <<= 1) {
        int x = buf[sb][t];
        if (t >= d) x += buf[sb][t - d];
        buf[sb ^ 1][t] = x;
        __syncthreads();
        sb ^= 1;
    }
    if (t < NB) {
        int excl = buf[sb][t] - v;
        btail[t] = excl;
        sbase[t] = excl;
    }
    if (t == 0) sbase[NB] = EE;
}

// scatter body. smemc layout (70720B total, 16B-aligned):
//   staged int2[8192] @0 (64KB) | hist[NB] | lstart[NB] | cursor[NB] |
//   gbase[NB] | sbuf[2][256]
__device__ __forceinline__ void scatter_work(char* smemc, int bid,
                               const int* __restrict__ src, const int* __restrict__ dst,
                               int* __restrict__ btail, int* __restrict__ packed) {
    int2* staged = (int2*)smemc;
    int* hist   = (int*)(smemc + 65536);
    int* lstart = hist + NB;
    int* cursor = lstart + NB;
    int* gbase  = cursor + NB;
    int* sbuf   = gbase + NB;   // [2][256]
    int t = threadIdx.x;
    for (int i = t; i < NB; i += 256) hist[i] = 0;
    __syncthreads();
    int base = bid * EPB;
    int cnt = min(EPB, EE - base);
    for (int i = t; i < cnt; i += 256)
        atomicAdd(&hist[dst[base + i] >> BSH], 1);
    __syncthreads();
    // exclusive scan of hist -> lstart, init cursor
    int v = (t < NB) ? hist[t] : 0;
    sbuf[t] = v;
    __syncthreads();
    int sb = 0;
    #pragma unroll
    for (int d = 1; d < 256; d <<= 1) {
        int x = sbuf[sb * 256 + t];
        if (t >= d) x += sbuf[sb * 256 + t - d];
        sbuf[(sb ^ 1) * 256 + t] = x;
        __syncthreads();
        sb ^= 1;
    }
    if (t < NB) {
        lstart[t] = sbuf[sb * 256 + t] - v;
        cursor[t] = sbuf[sb * 256 + t] - v;
    }
    __syncthreads();
    // rank + stage (re-read edges; L2-hot)
    for (int i = t; i < cnt; i += 256) {
        int d = dst[base + i], s = src[base + i];
        int r = atomicAdd(&cursor[d >> BSH], 1);
        staged[r] = make_int2(s, d);
    }
    // reserve global runs
    __syncthreads();
    for (int i = t; i < NB; i += 256) {
        int c = hist[i];
        if (c) gbase[i] = atomicAdd(&btail[i], c);
    }
    __syncthreads();
    // coalesced run writes
    for (int i = t; i < cnt; i += 256) {
        int2 e = staged[i];
        int b = e.y >> BSH;
        packed[gbase[b] + (i - lstart[b])] = ((e.y & 511) << 17) | e.x;
    }
}

// node_sort body, 256 threads (each thread owns 2 of the 512 bucket nodes).
// smemc: hist[512] | cursor[512] | scn[2][256]  = 6144 B.
__device__ __forceinline__ void sort_work(char* smemc, int b,
                          const int* __restrict__ packed, const int* __restrict__ sbase,
                          int* __restrict__ offs, int* __restrict__ sorted_src) {
    int* hist   = (int*)smemc;          // 512
    int* cursor = hist + 512;           // 512
    int* scn    = cursor + 512;         // 2*256
    int t = threadIdx.x;
    int s0 = sbase[b], s1 = sbase[b + 1];
    hist[t] = 0; hist[t + 256] = 0;
    __syncthreads();
    for (int e = s0 + t; e < s1; e += 256)
        atomicAdd(&hist[packed[e] >> 17], 1);
    __syncthreads();
    int a  = hist[2 * t];
    int bb = hist[2 * t + 1];
    scn[t] = a + bb;
    __syncthreads();
    int sb = 0;
    #pragma unroll
    for (int d = 1; d < 256; d <<= 1) {
        int x = scn[sb * 256 + t];
        if (t >= d) x += scn[sb * 256 + t - d];
        scn[(sb ^ 1) * 256 + t] = x;
        __syncthreads();
        sb ^= 1;
    }
    int inclPair = scn[sb * 256 + t];   // inclusive over node pairs
    int incl1 = inclPair;               // through node 2t+1
    int incl0 = inclPair - bb;          // through node 2t
    int node0 = (b << BSH) + 2 * t;
    if (node0 < NN)     offs[node0]     = s0 + incl0;  // inclusive end (CSR)
    if (node0 + 1 < NN) offs[node0 + 1] = s0 + incl1;
    cursor[2 * t]     = s0 + incl0 - a;                 // exclusive starts
    cursor[2 * t + 1] = s0 + incl1 - bb;
    __syncthreads();
    for (int e = s0 + t; e < s1; e += 256) {
        int p = packed[e];
        int pos = atomicAdd(&cursor[p >> 17], 1);
        sorted_src[pos] = p & 0x1FFFF;  // writes confined to 32KB window
    }
}

__launch_bounds__(256, 1)
__global__ void bucket_scatter(const int* __restrict__ src, const int* __restrict__ dst,
                               int* __restrict__ btail, int* __restrict__ packed) {
    __shared__ __align__(16) char smem[70720];
    scatter_work(smem, blockIdx.x, src, dst, btail, packed);
}

__launch_bounds__(256, 2)
__global__ void node_sort_k(const int* __restrict__ packed, const int* __restrict__ sbase,
                            int* __restrict__ offs, int* __restrict__ sorted_src) {
    __shared__ __align__(16) char smem[6144];
    sort_work(smem, blockIdx.x, packed, sbase, offs, sorted_src);
}

// D1: blocks [0,196) bucket_scatter (critical path), [196,512) gemm [0,G1).
// Exactly 512 blocks = one full 2-blocks/CU batch.
__launch_bounds__(256, 2)
__global__ void gemm0_scatter(const float* __restrict__ x,
                              const unsigned short* __restrict__ WH,
                              const unsigned short* __restrict__ WL,
                              const float* __restrict__ BE,
                              float* __restrict__ q, unsigned short* __restrict__ kvout,
                              const int* __restrict__ src, const int* __restrict__ dst,
                              int* __restrict__ btail, int* __restrict__ packed) {
    __shared__ __align__(16) char smem[70720];
    if (blockIdx.x < A_BLOCKS)
        scatter_work(smem, blockIdx.x, src, dst, btail, packed);
    else
        gemm_body(smem, (blockIdx.x - A_BLOCKS) * 128, x, WH, WL, BE, 3,
                  q, kvout, nullptr, nullptr);
}

// D2: blocks [0,196) node_sort (needs D1's packed), rest gemm [G1,782).
// node_sort's serial ~20us hides under the gemm's second half.
__launch_bounds__(256, 2)
__global__ void gemm0_sort(const float* __restrict__ x,
                           const unsigned short* __restrict__ WH,
                           const unsigned short* __restrict__ WL,
                           const float* __restrict__ BE,
                           float* __restrict__ q, unsigned short* __restrict__ kvout,
                           const int* __restrict__ packed, const int* __restrict__ sbase,
                           int* __restrict__ offs, int* __restrict__ sorted_src) {
    __shared__ __align__(16) char smem[70720];
    if (blockIdx.x < NB)
        sort_work(smem, blockIdx.x, packed, sbase, offs, sorted_src);
    else
        gemm_body(smem, (G1 + blockIdx.x - NB) * 128, x, WH, WL, BE, 3,
                  q, kvout, nullptr, nullptr);
}

// ---------------------------------------------------------------------------
// Fused per-dst attention, single pass, bf16 packed interleaved kv[n][256]:
// group g (=sl) holds {k[4g..4g+3], v[4g..4g+3]} at byte offset g*16 -> one
// dwordx4 per lane per edge (512B contiguous per half-wave request).
// One wave per node. TWO edges per half-wave per iteration (half h takes
// edges {4i+2h, 4i+2h+1}): two independent gathers issued back-to-back ->
// 2x memory-level parallelism per wave vs the serialized 1-edge loop
// (VGPR=16 showed the compiler was not keeping gathers in flight).
// exp via native v_exp_f32: log2(e) folded into the q prescale.
// Divergence-free: all 64 lanes active every iteration; out-of-range edges
// are clamped duplicates with weight 0. q fp32 (aliases t: read-before-write).
// ---------------------------------------------------------------------------
__launch_bounds__(256, 4)
__global__ void fused_attn(const float* __restrict__ q,
                           const unsigned short* __restrict__ kv,
                           const int* __restrict__ offs, const int* __restrict__ sorted_src,
                           const float* __restrict__ rel_pri, float* __restrict__ t) {
    int wave = threadIdx.x >> 6, lane = threadIdx.x & 63;
    int n = blockIdx.x * 4 + wave;
    if (n >= NN) return;
    int half = lane >> 5;
    int sl = lane & 31;
    int hh = sl >> 2;
    int start = (n > 0) ? offs[n - 1] : 0;
    int cnt = offs[n] - start;

    float4 q4 = *(const float4*)&q[(size_t)n * 128 + sl * 4];
    // fold rel_pri/sqrt(dk) AND log2(e) into the q prescale: exp(p)=exp2(p')
    float scale = rel_pri[hh] * 0.25f * 1.44269504088896340736f;
    q4.x *= scale; q4.y *= scale; q4.z *= scale; q4.w *= scale;

    const unsigned short* kvp = kv + sl * 8;   // lane-fixed sub-offset
    const int* ss = sorted_src + start;

    float4 o4 = {0.f, 0.f, 0.f, 0.f};
    float denom = 0.f;

    int nIter = (cnt + 3) >> 2;   // 4 edges per wave-iteration (2 per half)
    #pragma unroll 2
    for (int it = 0; it < nIter; it++) {
        int j0 = 4 * it + 2 * half;
        int j1 = j0 + 1;
        float w0 = (j0 < cnt) ? 1.f : 0.f;
        float w1 = (j1 < cnt) ? 1.f : 0.f;
        int jj0 = (j0 < cnt) ? j0 : (cnt - 1);
        int jj1 = (j1 < cnt) ? j1 : (cnt - 1);
        int s0 = ss[jj0];
        int s1 = ss[jj1];
        uint4 ka = *(const uint4*)(kvp + (size_t)s0 * 256);  // k4 | v4, 16B
        uint4 kb = *(const uint4*)(kvp + (size_t)s1 * 256);  // independent

        float pa = q4.x * bf2f((unsigned short)(ka.x & 0xffff))
                 + q4.y * bf2f((unsigned short)(ka.x >> 16))
                 + q4.z * bf2f((unsigned short)(ka.y & 0xffff))
                 + q4.w * bf2f((unsigned short)(ka.y >> 16));
        float pb = q4.x * bf2f((unsigned short)(kb.x & 0xffff))
                 + q4.y * bf2f((unsigned short)(kb.x >> 16))
                 + q4.z * bf2f((unsigned short)(kb.y & 0xffff))
                 + q4.w * bf2f((unsigned short)(kb.y >> 16));
        pa += __shfl_xor(pa, 1);
        pa += __shfl_xor(pa, 2);
        pb += __shfl_xor(pb, 1);
        pb += __shfl_xor(pb, 2);
        float ea = __builtin_amdgcn_exp2f(pa) * w0;   // native v_exp_f32
        float eb = __builtin_amdgcn_exp2f(pb) * w1;
        denom += ea + eb;
        o4.x = fmaf(bf2f((unsigned short)(ka.z & 0xffff)), ea, o4.x);
        o4.y = fmaf(bf2f((unsigned short)(ka.z >> 16)),    ea, o4.y);
        o4.z = fmaf(bf2f((unsigned short)(ka.w & 0xffff)), ea, o4.z);
        o4.w = fmaf(bf2f((unsigned short)(ka.w >> 16)),    ea, o4.w);
        o4.x = fmaf(bf2f((unsigned short)(kb.z & 0xffff)), eb, o4.x);
        o4.y = fmaf(bf2f((unsigned short)(kb.z >> 16)),    eb, o4.y);
        o4.z = fmaf(bf2f((unsigned short)(kb.w & 0xffff)), eb, o4.z);
        o4.w = fmaf(bf2f((unsigned short)(kb.w >> 16)),    eb, o4.w);
    }

    // combine the two halves (all 64 lanes active)
    denom += __shfl_xor(denom, 32);
    o4.x += __shfl_xor(o4.x, 32);
    o4.y += __shfl_xor(o4.y, 32);
    o4.z += __shfl_xor(o4.z, 32);
    o4.w += __shfl_xor(o4.w, 32);

    if (half == 0) {
        float inv = (cnt > 0) ? 1.f / denom : 0.f;
        o4.x *= inv; o4.y *= inv; o4.z *= inv; o4.w *= inv;
        *(float4*)&t[(size_t)n * 128 + sl * 4] = o4;
    }
}

// ---------------------------------------------------------------------------
extern "C" void kernel_launch(void* const* d_in, const int* in_sizes, int n_in,
                              void* d_out, int out_size, void* d_ws, size_t ws_size,
                              hipStream_t stream) {
    const float* h    = (const float*)d_in[0];
    const int*   src  = (const int*)d_in[1];
    const int*   dst  = (const int*)d_in[2];
    const float* Wk   = (const float*)d_in[3];
    const float* bk   = (const float*)d_in[4];
    const float* Wq   = (const float*)d_in[5];
    const float* bq   = (const float*)d_in[6];
    const float* Wv   = (const float*)d_in[7];
    const float* bv   = (const float*)d_in[8];
    const float* Wa   = (const float*)d_in[9];
    const float* ba   = (const float*)d_in[10];
    const float* rel_att = (const float*)d_in[11];
    const float* rel_msg = (const float*)d_in[12];
    const float* rel_pri = (const float*)d_in[13];
    const float* skip    = (const float*)d_in[14];
    float* out = (float*)d_out;

    unsigned short* kvbuf = (unsigned short*)d_ws;            // N*256 bf16
    float* BE   = (float*)(kvbuf + (size_t)NN * 256);         // 4*128
    int* scratch = (int*)(BE + 512);                          // N ints
    int* bcnt  = scratch;                                     // NB
    int* btail = bcnt + NB;                                   // NB
    int* sbase = btail + NB;                                  // NB+1
    int* offs  = scratch + NN;                                // N
    int* bsum  = offs + NN;                                   // 128 (layout keep)
    int* sorted_src = bsum + 128;                             // E
    unsigned short* WH = (unsigned short*)(sorted_src + EE);  // 4*16384 bf16
    unsigned short* WL = WH + 4 * 16384;                      // 4*16384 bf16
    char* ws_end = (char*)(WL + 4 * 16384);
    size_t used = (size_t)(ws_end - (char*)d_ws);
    // packed edges: dedicated region if workspace allows (enables
    // gemm0 || scatter/sort overlap); else alias kvbuf (serial fallback).
    bool sep = (ws_size >= used + (size_t)EE * sizeof(int));
    int* packed = sep ? (int*)ws_end : (int*)kvbuf;
    float* q = out;                                // q lives in d_out; t aliases q
    float* t = out;

    hipMemsetAsync(bcnt, 0, NB * sizeof(int), stream);
    // prep_weights || bucket_hist in one dispatch
    prep_hist<<<256 + A_BLOCKS, 256, 0, stream>>>(Wq, Wk, Wv, Wa, bq, bk, bv, ba,
                                                  rel_att, rel_msg, WH, WL, BE,
                                                  dst, bcnt);
    bucket_scan<<<1, 256, 0, stream>>>(bcnt, btail, sbase);

    if (sep) {
        // D1: scatter || gemm[0,G1)  (exactly 512 blocks = one full batch)
        gemm0_scatter<<<A_BLOCKS + G1, 256, 0, stream>>>(
            h, WH, WL, BE, q, kvbuf, src, dst, btail, packed);
        // D2: node_sort || gemm[G1,782)  -> sort cost hidden under gemm
        gemm0_sort<<<NB + (GEMM_BLOCKS - G1), 256, 0, stream>>>(
            h, WH, WL, BE, q, kvbuf, packed, sbase, offs, sorted_src);
    } else {
        // serial fallback: packed aliases kvbuf, must finish CSR before gemm0
        bucket_scatter<<<A_BLOCKS, 256, 0, stream>>>(src, dst, btail, packed);
        node_sort_k<<<NB, 256, 0, stream>>>(packed, sbase, offs, sorted_src);
        gemm_reg<<<GEMM_BLOCKS, 256, 0, stream>>>(h, WH, WL, BE, 3, q, kvbuf,
                                                  nullptr, nullptr);
    }

    // fused single-pass attention (no atomics)
    fused_attn<<<(NN + 3) / 4, 256, 0, stream>>>(q, kvbuf, offs, sorted_src,
                                                 rel_pri, t);
    // final projection + skip-gate mix (in-place on d_out)
    gemm_reg<<<GEMM_BLOCKS, 256, 0, stream>>>(t, WH + 3 * 16384, WL + 3 * 16384,
                                              BE + 384, 1, out, nullptr,
                                              h, skip);
}